// Round 11
// baseline (1097.030 us; speedup 1.0000x reference)
//
#include <hip/hip_runtime.h>
#include <cstdint>
#include <cstddef>

#define TT 4
#define BB 8
#define CC 256
#define NN 1024
#define HEADS 8
#define DD 32

typedef __attribute__((ext_vector_type(4))) double f64x4;

// Fused conv1x1 (GEMM) + BatchNorm + LIF-over-time using fp64 MFMA.
// Block: 32(o) x 32(n) tile, 4 waves; wave w computes timestep t=w.
// BARRIER-FREE K-loop: W is LDS-resident per 256-k chunk (staged once,
// one barrier); X staging is WAVE-PRIVATE (wave t is the sole consumer of
// X-plane t) through a per-wave LDS double-buffer -- ordering is same-wave
// lgkmcnt only, no __syncthreads. 256 MFMAs stream per chunk per wave with
// staging fully overlapped; 8 independent waves/CU keep the f64 pipe fed.
// Swizzles identical to round 6 (reads 2-way = free). MFMA operand values
// and order identical to rounds 4-10 -> bit-identical output (absmax 0.0).
// C/D mapping of v_mfma_f64_16x16x4f64 recovered at runtime via probes.
template<typename InT, typename OutT, bool HAS_BIAS, bool ADD_BASE, bool TRIPLE, int CIN>
__device__ __forceinline__ void conv_body(
    const float* __restrict__ W0, const float* __restrict__ W1,
    const float* __restrict__ W2, const float* __restrict__ bias,
    const float* __restrict__ bn0, const float* __restrict__ bn1,
    const float* __restrict__ bn2,
    const InT* __restrict__ X,
    OutT* __restrict__ Out0, OutT* __restrict__ Out1, OutT* __restrict__ Out2,
    const float* __restrict__ base,
    int O)
{
    __shared__ __align__(16) float Ws[256][32];        // 32 KB: W^T chunk, swizzled
    __shared__ __align__(16) float Xw[TT][2][32][32];  // 32 KB: per-wave X dbuf, swizzled
    double* pre = (double*)&Ws[0][0];                  // [4][32][32] f64 overlay (32 KB)

    const int tid  = threadIdx.x;
    const int lane = tid & 63;
    const int wave = tid >> 6;          // == timestep t
    const int col  = lane & 15;
    const int rowg = lane >> 4;         // 0..3 (k-group)
    const int n0 = blockIdx.x * 32;
    const int b  = blockIdx.z;

    int o0;
    const float *W, *bn;
    OutT* Out;
    if constexpr (TRIPLE) {
        const int sel = blockIdx.y >> 3;
        o0 = (blockIdx.y & 7) * 32;
        W   = sel == 0 ? W0  : (sel == 1 ? W1  : W2);
        bn  = sel == 0 ? bn0 : (sel == 1 ? bn1 : bn2);
        Out = sel == 0 ? Out0 : (sel == 1 ? Out1 : Out2);
    } else {
        o0 = blockIdx.y * 32;
        W = W0; bn = bn0; Out = Out0;
    }

    // per-lane swizzled read columns (o/n offset col and col+16)
    const int cb0 = (col + 8 * rowg) & 31;
    const int cb1 = (col + 16 + 8 * rowg) & 31;

    // X staging mapping (wave-private): lane covers rows (lane>>3)+8j, quad lane&7
    const int xl_row = lane >> 3;
    const int xl_n4  = lane & 7;

    // ---- runtime layout probes (exact integer arithmetic in f64) ----
    f64x4 p1 = {0.0, 0.0, 0.0, 0.0};
    f64x4 p2 = {0.0, 0.0, 0.0, 0.0};
    const double lanev = (double)col;
    p1 = __builtin_amdgcn_mfma_f64_16x16x4f64(lanev, 1.0, p1, 0, 0, 0);
    p2 = __builtin_amdgcn_mfma_f64_16x16x4f64(1.0, lanev, p2, 0, 0, 0);
    int o_idx[4], n_idx[4];
#pragma unroll
    for (int r = 0; r < 4; ++r) {
        o_idx[r] = (int)(p1[r] * 0.25);
        n_idx[r] = (int)(p2[r] * 0.25);
    }

    f64x4 acc[2][2];
#pragma unroll
    for (int mf = 0; mf < 2; ++mf)
#pragma unroll
        for (int nf = 0; nf < 2; ++nf)
            acc[mf][nf] = (f64x4){0.0, 0.0, 0.0, 0.0};

    float4 rX[4];
    uchar4 rXu[4];

    auto issue_x = [&](int c0) {        // absolute k base; 4 rows x 8 j-groups
#pragma unroll
        for (int j = 0; j < 4; ++j) {
            const int kk = xl_row + j * 8;
            const size_t goff =
                (((size_t)wave * BB + b) * CIN + c0 + kk) * NN + n0 + xl_n4 * 4;
            if constexpr (__is_same(InT, uint8_t)) {
                rXu[j] = *reinterpret_cast<const uchar4*>(&X[goff]);
            } else {
                rX[j] = *reinterpret_cast<const float4*>(&X[goff]);
            }
        }
    };
    auto write_x = [&](int buf) {
#pragma unroll
        for (int j = 0; j < 4; ++j) {
            const int kk = xl_row + j * 8;
            float4 xv;
            if constexpr (__is_same(InT, uint8_t)) {
                xv = make_float4((float)rXu[j].x, (float)rXu[j].y,
                                 (float)rXu[j].z, (float)rXu[j].w);
            } else {
                xv = rX[j];
            }
            const int cs = (xl_n4 * 4 + 8 * (kk & 3)) & 31;
            *reinterpret_cast<float4*>(&Xw[wave][buf][kk][cs]) = xv;
        }
    };
    auto stage_w = [&](int cbase) {     // 32 o x 256 k chunk -> Ws[k][o'] swizzled
#pragma unroll
        for (int j = 0; j < 8; ++j) {
            const int ol = tid >> 3;
            const int cq = (tid & 7) + j * 8;          // k-quad 0..63
            float4 wv = *reinterpret_cast<const float4*>(
                &W[(size_t)(o0 + ol) * CIN + cbase + cq * 4]);
            const int k0 = cq * 4;
            Ws[k0 + 0][(ol + 0 ) & 31] = wv.x;
            Ws[k0 + 1][(ol + 8 ) & 31] = wv.y;
            Ws[k0 + 2][(ol + 16) & 31] = wv.z;
            Ws[k0 + 3][(ol + 24) & 31] = wv.w;
        }
    };

    constexpr int NCH = CIN / 256;
    int cur = 0;
    for (int ch = 0; ch < NCH; ++ch) {
        const int cstart = ch * 256;
        if (ch > 0) __syncthreads();         // all waves done reading old Ws
        issue_x(cstart);                     // overlap X load with W staging
        stage_w(cstart);
        write_x(cur);
        __syncthreads();                     // Ws ready (once per chunk)

#pragma unroll
        for (int ks = 0; ks < 8; ++ks) {     // 8 K-steps of 32, barrier-free
            if (ks < 7) issue_x(cstart + (ks + 1) * 32);
            __builtin_amdgcn_s_setprio(1);
#pragma unroll
            for (int k0 = 0; k0 < 32; k0 += 4) {
                const int kr = ks * 32 + k0 + rowg;   // Ws row (kr&3 == rowg)
                const int xr = k0 + rowg;             // Xw row
                double av0 = (double)Ws[kr][cb0];
                double av1 = (double)Ws[kr][cb1];
                double bv0 = (double)Xw[wave][cur][xr][cb0];
                double bv1 = (double)Xw[wave][cur][xr][cb1];
                acc[0][0] = __builtin_amdgcn_mfma_f64_16x16x4f64(av0, bv0, acc[0][0], 0, 0, 0);
                acc[1][0] = __builtin_amdgcn_mfma_f64_16x16x4f64(av1, bv0, acc[1][0], 0, 0, 0);
                acc[0][1] = __builtin_amdgcn_mfma_f64_16x16x4f64(av0, bv1, acc[0][1], 0, 0, 0);
                acc[1][1] = __builtin_amdgcn_mfma_f64_16x16x4f64(av1, bv1, acc[1][1], 0, 0, 0);
            }
            __builtin_amdgcn_s_setprio(0);
            if (ks < 7) write_x(cur ^ 1);    // same-wave lgkmcnt ordering only
            cur ^= 1;
        }
    }

    // ---- epilogue: dump pre-activations (overlay on Ws), then BN + LIF ----
    __syncthreads();                         // all waves done with Ws reads
#pragma unroll
    for (int mf = 0; mf < 2; ++mf)
#pragma unroll
        for (int r = 0; r < 4; ++r)
#pragma unroll
            for (int nf = 0; nf < 2; ++nf)
                pre[((size_t)wave * 32 + mf * 16 + o_idx[r]) * 32
                    + nf * 16 + n_idx[r]] = acc[mf][nf][r];
    __syncthreads();

    const int nl = tid & 31;
    const int obase = (tid >> 5) * 4;
#pragma unroll
    for (int i = 0; i < 4; ++i) {
        const int ol = obase + i;
        const int o  = o0 + ol;
        const double g   = (double)bn[0 * O + o];
        const double be  = (double)bn[1 * O + o];
        const double mu  = (double)bn[2 * O + o];
        const double var = (double)bn[3 * O + o];
        const double scale = g / sqrt(var + 1e-5);
        double bi = 0.0;
        if constexpr (HAS_BIAS) bi = (double)bias[o];
        double v = 0.0;
#pragma unroll
        for (int t = 0; t < TT; ++t) {
            double val = (pre[((size_t)t * 32 + ol) * 32 + nl] + bi - mu) * scale + be;
            v = v + (val - v) * 0.5;
            double s = (v >= 1.0) ? 1.0 : 0.0;
            size_t idx = (((size_t)t * BB + b) * O + o) * NN + n0 + nl;
            if constexpr (ADD_BASE) {
                Out[idx] = (OutT)((double)base[idx] + s);
            } else {
                Out[idx] = (OutT)s;
            }
            v = v * (1.0 - s);
        }
    }
}

// distinct kernel names for unambiguous profiling attribution
__global__ __launch_bounds__(256, 2) void conv_qkv(
    const float* W0, const float* W1, const float* W2,
    const float* bn0, const float* bn1, const float* bn2,
    const float* X, float* O0, float* O1, float* O2)
{
    conv_body<float, float, false, false, true, 256>(
        W0, W1, W2, nullptr, bn0, bn1, bn2, X, O0, O1, O2, nullptr, 256);
}
__global__ __launch_bounds__(256, 2) void conv_proj(
    const float* W, const float* bias, const float* bn,
    const float* X, float* Out, const float* base)
{
    conv_body<float, float, true, true, false, 256>(
        W, nullptr, nullptr, bias, bn, nullptr, nullptr, X, Out, nullptr,
        nullptr, base, 256);
}
__global__ __launch_bounds__(256, 2) void conv_mlp1(
    const float* W, const float* bias, const float* bn,
    const float* X, uint8_t* Out)
{
    conv_body<float, uint8_t, true, false, false, 256>(
        W, nullptr, nullptr, bias, bn, nullptr, nullptr, X, Out, nullptr,
        nullptr, nullptr, 1024);
}
__global__ __launch_bounds__(256, 2) void conv_mlp2(
    const float* W, const float* bias, const float* bn,
    const uint8_t* X, float* Out, const float* base)
{
    conv_body<uint8_t, float, true, true, false, 1024>(
        W, nullptr, nullptr, bias, bn, nullptr, nullptr, X, Out, nullptr,
        nullptr, base, 256);
}

// kv[t,b,h,d,e] = sum_n k[t,b,h*32+d,n] * v[t,b,h*32+e,n]  (exact int in fp32)
__global__ __launch_bounds__(256) void kv_kernel(
    const float* __restrict__ k_s, const float* __restrict__ v_s,
    float* __restrict__ kv)
{
    const int blk = blockIdx.x;
    const int h = blk & 7;
    const int m = blk >> 3;
    __shared__ float ks[32][65];
    __shared__ float vs[32][65];
    const int tid = threadIdx.x;
    const int d = tid >> 3;
    const int e0 = (tid & 7) * 4;
    float acc[4] = {0.f, 0.f, 0.f, 0.f};
    const size_t basek = ((size_t)m * CC + h * DD) * NN;
    for (int nc = 0; nc < NN; nc += 64) {
        for (int i = tid; i < 2048; i += 256) {
            int r = i >> 6, nl = i & 63;
            ks[r][nl] = k_s[basek + (size_t)r * NN + nc + nl];
            vs[r][nl] = v_s[basek + (size_t)r * NN + nc + nl];
        }
        __syncthreads();
        for (int nl = 0; nl < 64; ++nl) {
            float kd = ks[d][nl];
#pragma unroll
            for (int j = 0; j < 4; ++j) acc[j] += kd * vs[e0 + j][nl];
        }
        __syncthreads();
    }
#pragma unroll
    for (int j = 0; j < 4; ++j)
        kv[(size_t)blk * 1024 + d * 32 + e0 + j] = acc[j];
}

// a = 0.125 * q @ kv -> LIF(v_th=0.5); exact dyadic arithmetic in fp32.
__global__ __launch_bounds__(256) void attn_a_lif(
    const float* __restrict__ q_s, const float* __restrict__ kv,
    float* __restrict__ a_s)
{
    const int tid = threadIdx.x;
    const int n = blockIdx.x * 256 + tid;
    const int c = blockIdx.y;
    const int b = blockIdx.z;
    const int h = c >> 5;
    const int e = c & 31;
    __shared__ float kvs[TT][32];
    if (tid < 128) {
        int t = tid >> 5, d2 = tid & 31;
        kvs[t][d2] = kv[(((size_t)t * BB + b) * HEADS + h) * 1024 + d2 * 32 + e];
    }
    __syncthreads();
    float val[TT];
#pragma unroll
    for (int t = 0; t < TT; ++t) {
        float s = 0.f;
        const size_t qb = (((size_t)t * BB + b) * CC + h * DD) * NN + n;
#pragma unroll 8
        for (int d2 = 0; d2 < 32; ++d2)
            s += q_s[qb + (size_t)d2 * NN] * kvs[t][d2];
        val[t] = s * 0.125f;
    }
    float v = 0.f;
#pragma unroll
    for (int t = 0; t < TT; ++t) {
        v = v + (val[t] - v) * 0.5f;
        float s = (v >= 0.5f) ? 1.f : 0.f;
        a_s[(((size_t)t * BB + b) * CC + c) * NN + n] = s;
        v = v * (1.f - s);
    }
}

extern "C" void kernel_launch(void* const* d_in, const int* in_sizes, int n_in,
                              void* d_out, int out_size, void* d_ws, size_t ws_size,
                              hipStream_t stream)
{
    const float* x       = (const float*)d_in[0];
    const float* q_w     = (const float*)d_in[1];
    const float* q_bn    = (const float*)d_in[2];
    const float* k_w     = (const float*)d_in[3];
    const float* k_bn    = (const float*)d_in[4];
    const float* v_w     = (const float*)d_in[5];
    const float* v_bn    = (const float*)d_in[6];
    const float* proj_w  = (const float*)d_in[7];
    const float* proj_b  = (const float*)d_in[8];
    const float* proj_bn = (const float*)d_in[9];
    const float* mlp1_w  = (const float*)d_in[10];
    const float* mlp1_b  = (const float*)d_in[11];
    const float* mlp1_bn = (const float*)d_in[12];
    const float* mlp2_w  = (const float*)d_in[13];
    const float* mlp2_b  = (const float*)d_in[14];
    const float* mlp2_bn = (const float*)d_in[15];

    const size_t SZ = (size_t)TT * BB * CC * NN;   // 8388608 elements
    char* ws = (char*)d_ws;
    float*   q_s   = (float*)(ws);
    float*   k_s   = (float*)(ws + SZ * 4);
    float*   v_s   = (float*)(ws + 2 * SZ * 4);
    float*   a_s   = (float*)(ws + 3 * SZ * 4);
    float*   kvb   = (float*)(ws + 4 * SZ * 4);    // 1 MB
    float*   x_new = (float*)(ws);                 // reuses q_s region
    uint8_t* h1    = (uint8_t*)(ws + SZ * 4);      // reuses k_s region (33.5 MB)

    dim3 blk(256);
    dim3 gqkv(NN / 32, 3 * 256 / 32, BB);   // (32, 24, 8)
    dim3 g256(NN / 32, 256 / 32, BB);       // (32, 8, 8)
    dim3 g1024(NN / 32, 1024 / 32, BB);     // (32, 32, 8)

    // Q/K/V conv + BN + LIF -> spike trains (f32 0/1), one fused dispatch
    conv_qkv<<<gqkv, blk, 0, stream>>>(q_w, k_w, v_w, q_bn, k_bn, v_bn,
                                       x, q_s, k_s, v_s);

    // attention: kv = k^T v, then a = 0.125 * q kv -> LIF(0.5)
    kv_kernel<<<dim3(TT * BB * HEADS), blk, 0, stream>>>(k_s, v_s, kvb);
    attn_a_lif<<<dim3(4, 256, 8), blk, 0, stream>>>(q_s, kvb, a_s);

    // proj conv + bias + BN + LIF, fused residual: x_new = x + ssa
    conv_proj<<<g256, blk, 0, stream>>>(proj_w, proj_b, proj_bn, a_s, x_new, x);

    // MLP: 256 -> 1024 (spikes as uint8) -> 256, fused residual to d_out
    conv_mlp1<<<g1024, blk, 0, stream>>>(mlp1_w, mlp1_b, mlp1_bn, x_new, h1);
    conv_mlp2<<<g256, blk, 0, stream>>>(mlp2_w, mlp2_b, mlp2_bn, h1,
                                        (float*)d_out, x_new);
}

// Round 12
// 937.444 us; speedup vs baseline: 1.1702x; 1.1702x over previous
//
#include <hip/hip_runtime.h>
#include <cstdint>
#include <cstddef>

#define TT 4
#define BB 8
#define CC 256
#define NN 1024
#define HEADS 8
#define DD 32

typedef __attribute__((ext_vector_type(4))) float  f32x4;
typedef __attribute__((ext_vector_type(8))) short  s16x8;

__device__ __forceinline__ unsigned short bf16_rne(float x) {
    unsigned u = __float_as_uint(x);
    return (unsigned short)((u + 0x7FFFu + ((u >> 16) & 1u)) >> 16);
}
__device__ __forceinline__ float bf16f(unsigned short h) {
    return __uint_as_float(((unsigned)h) << 16);
}

// Fused conv1x1 + BN + LIF via bf16-split MFMA with margin-screened f64
// recompute. Block 64o x 64n, 4 waves (wave = timestep t). Each wave holds
// acc[4][4] f32x4 (64 VGPR) covering 64x64 for its t.
// W split into (wh, wl) bf16; X split too unless SPLIT_IN=false (exact 0/1
// spike inputs). GEMM: acc += wh*xh + wl*xh (+ wh*xl). Per-term error
// ~2^-17, accum sigma ~1e-5. Epilogue: f32 LIF; columns with any
// |v - 1| < EPS are recomputed exactly in f64 (identical to rounds 1-11
// numerics) -- ~0.2% of threads. k-permutation invariance: A and B frags
// use identical (kgroup,j) indexing, so the actual per-lane k order of the
// MFMA is irrelevant. C/D map: col=lane&15, row=(lane>>4)*4+reg (HW-verified).
// LDS: XOR-swizzled unpadded bf16 tiles (16B-unit ^ (row>>1)&3): reads ~2-way.
template<typename InT, typename OutT, bool HAS_BIAS, bool ADD_BASE, bool TRIPLE, bool SPLIT_IN, int CIN>
__device__ __forceinline__ void conv_bf16_body(
    const float* __restrict__ W0, const float* __restrict__ W1,
    const float* __restrict__ W2, const float* __restrict__ bias,
    const float* __restrict__ bn0, const float* __restrict__ bn1,
    const float* __restrict__ bn2,
    const InT* __restrict__ X,
    OutT* __restrict__ Out0, OutT* __restrict__ Out1, OutT* __restrict__ Out2,
    const float* __restrict__ base, int O)
{
    constexpr int HL = SPLIT_IN ? 2 : 1;
    __shared__ __align__(16) unsigned short Wt[2][2][64][32];       // 16 KB
    __shared__ __align__(16) unsigned short Xt[2][HL][TT][64][32];  // 64/32 KB
    float* pre = (float*)&Xt[0][0][0][0][0];   // [2][64][64] f32 overlay (32 KB)

    constexpr float EPS = 3e-4f;

    const int tid  = threadIdx.x;
    const int lane = tid & 63;
    const int wave = tid >> 6;          // == timestep t
    const int lr   = lane & 15;
    const int lk   = lane >> 4;
    const int n0 = blockIdx.x * 64;
    const int b  = blockIdx.z;

    int o0;
    const float *W, *bn;
    OutT* Out;
    if constexpr (TRIPLE) {
        const int sel = blockIdx.y >> 2;
        o0 = (blockIdx.y & 3) * 64;
        W   = sel == 0 ? W0  : (sel == 1 ? W1  : W2);
        bn  = sel == 0 ? bn0 : (sel == 1 ? bn1 : bn2);
        Out = sel == 0 ? Out0 : (sel == 1 ? Out1 : Out2);
    } else {
        o0 = blockIdx.y * 64;
        W = W0; bn = bn0; Out = Out0;
    }

    f32x4 acc[4][4];
#pragma unroll
    for (int mf = 0; mf < 4; ++mf)
#pragma unroll
        for (int nf = 0; nf < 4; ++nf)
            acc[mf][nf] = (f32x4){0.f, 0.f, 0.f, 0.f};

    // staging registers
    float         rrf[32];
    unsigned char rr8[32];
    float4 rw0, rw1;
    const int wo = tid >> 2, wkq = tid & 3;   // W: 64 o x 4 k-octets

    auto issue_loads = [&](int c0) {
        rw0 = *reinterpret_cast<const float4*>(&W[(size_t)(o0 + wo) * CIN + c0 + wkq * 8]);
        rw1 = *reinterpret_cast<const float4*>(&W[(size_t)(o0 + wo) * CIN + c0 + wkq * 8 + 4]);
#pragma unroll
        for (int k = 0; k < 32; ++k) {
            const size_t g = (((size_t)wave * BB + b) * CIN + c0 + k) * NN + n0 + lane;
            if constexpr (__is_same(InT, uint8_t)) rr8[k] = X[g];
            else                                   rrf[k] = X[g];
        }
    };
    auto write_tiles = [&](int buf) {
        // W: k = wkq*8 + e
        {
            s16x8 hv, lv;
#pragma unroll
            for (int e = 0; e < 8; ++e) {
                float f = (e < 4) ? ((const float*)&rw0)[e] : ((const float*)&rw1)[e - 4];
                unsigned short h = bf16_rne(f);
                hv[e] = (short)h;
                lv[e] = (short)bf16_rne(f - bf16f(h));
            }
            const int u = (wkq ^ ((wo >> 1) & 3)) * 8;
            *reinterpret_cast<s16x8*>(&Wt[buf][0][wo][u]) = hv;
            *reinterpret_cast<s16x8*>(&Wt[buf][1][wo][u]) = lv;
        }
        // X: n = lane, k = g*4 + e
#pragma unroll
        for (int g = 0; g < 8; ++g) {
            ushort4 h4, l4;
#pragma unroll
            for (int e = 0; e < 4; ++e) {
                float f;
                if constexpr (__is_same(InT, uint8_t)) f = (float)rr8[g * 4 + e];
                else                                   f = rrf[g * 4 + e];
                unsigned short h = bf16_rne(f);
                ((unsigned short*)&h4)[e] = h;
                if constexpr (SPLIT_IN)
                    ((unsigned short*)&l4)[e] = bf16_rne(f - bf16f(h));
            }
            const int u = ((g >> 1) ^ ((lane >> 1) & 3)) * 8 + (g & 1) * 4;
            *reinterpret_cast<ushort4*>(&Xt[buf][0][wave][lane][u]) = h4;
            if constexpr (SPLIT_IN)
                *reinterpret_cast<ushort4*>(&Xt[buf][SPLIT_IN ? 1 : 0][wave][lane][u]) = l4;
        }
    };

    issue_loads(0);
    write_tiles(0);
    __syncthreads();

    int cur = 0;
    for (int c0 = 32; c0 <= CIN; c0 += 32) {
        const bool hn = (c0 < CIN);
        if (hn) issue_loads(c0);
        __builtin_amdgcn_s_setprio(1);
        s16x8 aH[4], aL[4], bH[4], bL[4];
#pragma unroll
        for (int mf = 0; mf < 4; ++mf) {
            const int o = mf * 16 + lr;
            const int u = (lk ^ ((o >> 1) & 3)) * 8;
            aH[mf] = *reinterpret_cast<const s16x8*>(&Wt[cur][0][o][u]);
            aL[mf] = *reinterpret_cast<const s16x8*>(&Wt[cur][1][o][u]);
        }
#pragma unroll
        for (int nf = 0; nf < 4; ++nf) {
            const int n = nf * 16 + lr;
            const int u = (lk ^ ((n >> 1) & 3)) * 8;
            bH[nf] = *reinterpret_cast<const s16x8*>(&Xt[cur][0][wave][n][u]);
            if constexpr (SPLIT_IN)
                bL[nf] = *reinterpret_cast<const s16x8*>(&Xt[cur][SPLIT_IN ? 1 : 0][wave][n][u]);
        }
#pragma unroll
        for (int mf = 0; mf < 4; ++mf)
#pragma unroll
            for (int nf = 0; nf < 4; ++nf) {
                acc[mf][nf] = __builtin_amdgcn_mfma_f32_16x16x32_bf16(
                    aH[mf], bH[nf], acc[mf][nf], 0, 0, 0);
                acc[mf][nf] = __builtin_amdgcn_mfma_f32_16x16x32_bf16(
                    aL[mf], bH[nf], acc[mf][nf], 0, 0, 0);
                if constexpr (SPLIT_IN)
                    acc[mf][nf] = __builtin_amdgcn_mfma_f32_16x16x32_bf16(
                        aH[mf], bL[nf], acc[mf][nf], 0, 0, 0);
            }
        __builtin_amdgcn_s_setprio(0);
        if (hn) write_tiles(cur ^ 1);
        __syncthreads();
        cur ^= 1;
    }

    // ---- epilogue ----
    const int nl = tid & 63;
    const int og = wave;

    auto dump = [&](int slot) {
#pragma unroll
        for (int mf = 0; mf < 4; ++mf)
#pragma unroll
            for (int nf = 0; nf < 4; ++nf)
#pragma unroll
                for (int r = 0; r < 4; ++r)
                    pre[(size_t)(slot * 64 + mf * 16 + lk * 4 + r) * 64
                        + nf * 16 + lr] = acc[mf][nf][r];
    };

    // f32 BN constants: val = pre*sf + cf
    float sf[16], cf[16];
#pragma unroll
    for (int i = 0; i < 16; ++i) {
        const int o = o0 + og * 16 + i;
        const double scale = (double)bn[0 * O + o] / sqrt((double)bn[3 * O + o] + 1e-5);
        double bi = 0.0;
        if constexpr (HAS_BIAS) bi = (double)bias[o];
        sf[i] = (float)scale;
        cf[i] = (float)((bi - (double)bn[2 * O + o]) * scale + (double)bn[1 * O + o]);
    }

    unsigned flags = 0;
    float vst[16];

    // Round A: t = 0,1
    if (wave < 2) dump(wave);
    __syncthreads();
#pragma unroll
    for (int i = 0; i < 16; ++i) {
        const int o = o0 + og * 16 + i;
        float v = 0.f;
#pragma unroll
        for (int t = 0; t < 2; ++t) {
            const float val = fmaf(pre[(size_t)(t * 64 + og * 16 + i) * 64 + nl], sf[i], cf[i]);
            v = v + (val - v) * 0.5f;
            if (fabsf(v - 1.0f) < EPS) flags |= (1u << i);
            const float s = (v >= 1.0f) ? 1.f : 0.f;
            const size_t idx = (((size_t)t * BB + b) * O + o) * NN + n0 + nl;
            if constexpr (ADD_BASE) Out[idx] = (OutT)(base[idx] + s);
            else                    Out[idx] = (OutT)s;
            v *= (1.f - s);
        }
        vst[i] = v;
    }
    __syncthreads();
    // Round B: t = 2,3
    if (wave >= 2) dump(wave - 2);
    __syncthreads();
#pragma unroll
    for (int i = 0; i < 16; ++i) {
        const int o = o0 + og * 16 + i;
        float v = vst[i];
#pragma unroll
        for (int t = 2; t < 4; ++t) {
            const float val = fmaf(pre[(size_t)((t - 2) * 64 + og * 16 + i) * 64 + nl], sf[i], cf[i]);
            v = v + (val - v) * 0.5f;
            if (fabsf(v - 1.0f) < EPS) flags |= (1u << i);
            const float s = (v >= 1.0f) ? 1.f : 0.f;
            const size_t idx = (((size_t)t * BB + b) * O + o) * NN + n0 + nl;
            if constexpr (ADD_BASE) Out[idx] = (OutT)(base[idx] + s);
            else                    Out[idx] = (OutT)s;
            v *= (1.f - s);
        }
    }

    // ---- exact f64 recompute of flagged columns (rare) ----
    if (flags) {
#pragma unroll 1
        for (int i = 0; i < 16; ++i) {
            if (!(flags & (1u << i))) continue;
            const int o = o0 + og * 16 + i;
            const int n = n0 + nl;
            double s0 = 0.0, s1 = 0.0, s2 = 0.0, s3 = 0.0;
#pragma unroll 2
            for (int k = 0; k < CIN; ++k) {
                const double w = (double)W[(size_t)o * CIN + k];
                const size_t xb = (size_t)k * NN + n;
                s0 += w * (double)X[((size_t)(0 * BB + b) * CIN) * NN + xb];
                s1 += w * (double)X[((size_t)(1 * BB + b) * CIN) * NN + xb];
                s2 += w * (double)X[((size_t)(2 * BB + b) * CIN) * NN + xb];
                s3 += w * (double)X[((size_t)(3 * BB + b) * CIN) * NN + xb];
            }
            double sums[4] = {s0, s1, s2, s3};
            const double g   = (double)bn[0 * O + o];
            const double be  = (double)bn[1 * O + o];
            const double mu  = (double)bn[2 * O + o];
            const double var = (double)bn[3 * O + o];
            const double scale = g / sqrt(var + 1e-5);
            double bi = 0.0;
            if constexpr (HAS_BIAS) bi = (double)bias[o];
            double v = 0.0;
#pragma unroll
            for (int t = 0; t < TT; ++t) {
                const double val = (sums[t] + bi - mu) * scale + be;
                v = v + (val - v) * 0.5;
                const double s = (v >= 1.0) ? 1.0 : 0.0;
                const size_t idx = (((size_t)t * BB + b) * O + o) * NN + n0 + nl;
                if constexpr (ADD_BASE) Out[idx] = (OutT)((double)base[idx] + s);
                else                    Out[idx] = (OutT)s;
                v = v * (1.0 - s);
            }
        }
    }
}

__global__ __launch_bounds__(256, 2) void conv_qkv(
    const float* W0, const float* W1, const float* W2,
    const float* bn0, const float* bn1, const float* bn2,
    const float* X, float* O0, float* O1, float* O2)
{
    conv_bf16_body<float, float, false, false, true, true, 256>(
        W0, W1, W2, nullptr, bn0, bn1, bn2, X, O0, O1, O2, nullptr, 256);
}
__global__ __launch_bounds__(256, 2) void conv_proj(
    const float* W, const float* bias, const float* bn,
    const float* X, float* Out, const float* base)
{
    conv_bf16_body<float, float, true, true, false, false, 256>(
        W, nullptr, nullptr, bias, bn, nullptr, nullptr, X, Out, nullptr,
        nullptr, base, 256);
}
__global__ __launch_bounds__(256, 2) void conv_mlp1(
    const float* W, const float* bias, const float* bn,
    const float* X, uint8_t* Out)
{
    conv_bf16_body<float, uint8_t, true, false, false, true, 256>(
        W, nullptr, nullptr, bias, bn, nullptr, nullptr, X, Out, nullptr,
        nullptr, nullptr, 1024);
}
__global__ __launch_bounds__(256, 2) void conv_mlp2(
    const float* W, const float* bias, const float* bn,
    const uint8_t* X, float* Out, const float* base)
{
    conv_bf16_body<uint8_t, float, true, true, false, false, 1024>(
        W, nullptr, nullptr, bias, bn, nullptr, nullptr, X, Out, nullptr,
        nullptr, base, 256);
}

// kv[t,b,h,d,e] = sum_n k[...] * v[...]  (exact integer arithmetic in fp32)
__global__ __launch_bounds__(256) void kv_kernel(
    const float* __restrict__ k_s, const float* __restrict__ v_s,
    float* __restrict__ kv)
{
    const int blk = blockIdx.x;
    const int h = blk & 7;
    const int m = blk >> 3;
    __shared__ float ks[32][65];
    __shared__ float vs[32][65];
    const int tid = threadIdx.x;
    const int d = tid >> 3;
    const int e0 = (tid & 7) * 4;
    float acc[4] = {0.f, 0.f, 0.f, 0.f};
    const size_t basek = ((size_t)m * CC + h * DD) * NN;
    for (int nc = 0; nc < NN; nc += 64) {
        for (int i = tid; i < 2048; i += 256) {
            int r = i >> 6, nl = i & 63;
            ks[r][nl] = k_s[basek + (size_t)r * NN + nc + nl];
            vs[r][nl] = v_s[basek + (size_t)r * NN + nc + nl];
        }
        __syncthreads();
        for (int nl = 0; nl < 64; ++nl) {
            float kd = ks[d][nl];
#pragma unroll
            for (int j = 0; j < 4; ++j) acc[j] += kd * vs[e0 + j][nl];
        }
        __syncthreads();
    }
#pragma unroll
    for (int j = 0; j < 4; ++j)
        kv[(size_t)blk * 1024 + d * 32 + e0 + j] = acc[j];
}

// a = 0.125 * q @ kv -> LIF(v_th=0.5); exact dyadic arithmetic in fp32.
__global__ __launch_bounds__(256) void attn_a_lif(
    const float* __restrict__ q_s, const float* __restrict__ kv,
    float* __restrict__ a_s)
{
    const int tid = threadIdx.x;
    const int n = blockIdx.x * 256 + tid;
    const int c = blockIdx.y;
    const int b = blockIdx.z;
    const int h = c >> 5;
    const int e = c & 31;
    __shared__ float kvs[TT][32];
    if (tid < 128) {
        int t = tid >> 5, d2 = tid & 31;
        kvs[t][d2] = kv[(((size_t)t * BB + b) * HEADS + h) * 1024 + d2 * 32 + e];
    }
    __syncthreads();
    float val[TT];
#pragma unroll
    for (int t = 0; t < TT; ++t) {
        float s = 0.f;
        const size_t qb = (((size_t)t * BB + b) * CC + h * DD) * NN + n;
#pragma unroll 8
        for (int d2 = 0; d2 < 32; ++d2)
            s += q_s[qb + (size_t)d2 * NN] * kvs[t][d2];
        val[t] = s * 0.125f;
    }
    float v = 0.f;
#pragma unroll
    for (int t = 0; t < TT; ++t) {
        v = v + (val[t] - v) * 0.5f;
        float s = (v >= 0.5f) ? 1.f : 0.f;
        a_s[(((size_t)t * BB + b) * CC + c) * NN + n] = s;
        v = v * (1.f - s);
    }
}

extern "C" void kernel_launch(void* const* d_in, const int* in_sizes, int n_in,
                              void* d_out, int out_size, void* d_ws, size_t ws_size,
                              hipStream_t stream)
{
    const float* x       = (const float*)d_in[0];
    const float* q_w     = (const float*)d_in[1];
    const float* q_bn    = (const float*)d_in[2];
    const float* k_w     = (const float*)d_in[3];
    const float* k_bn    = (const float*)d_in[4];
    const float* v_w     = (const float*)d_in[5];
    const float* v_bn    = (const float*)d_in[6];
    const float* proj_w  = (const float*)d_in[7];
    const float* proj_b  = (const float*)d_in[8];
    const float* proj_bn = (const float*)d_in[9];
    const float* mlp1_w  = (const float*)d_in[10];
    const float* mlp1_b  = (const float*)d_in[11];
    const float* mlp1_bn = (const float*)d_in[12];
    const float* mlp2_w  = (const float*)d_in[13];
    const float* mlp2_b  = (const float*)d_in[14];
    const float* mlp2_bn = (const float*)d_in[15];

    const size_t SZ = (size_t)TT * BB * CC * NN;   // 8388608 elements
    char* ws = (char*)d_ws;
    float*   q_s   = (float*)(ws);
    float*   k_s   = (float*)(ws + SZ * 4);
    float*   v_s   = (float*)(ws + 2 * SZ * 4);
    float*   a_s   = (float*)(ws + 3 * SZ * 4);
    float*   kvb   = (float*)(ws + 4 * SZ * 4);    // 1 MB
    float*   x_new = (float*)(ws);                 // reuses q_s region
    uint8_t* h1    = (uint8_t*)(ws + SZ * 4);      // reuses k_s region

    dim3 blk(256);
    dim3 gqkv(NN / 64, 3 * 256 / 64, BB);   // (16, 12, 8)
    dim3 g256(NN / 64, 256 / 64, BB);       // (16, 4, 8)
    dim3 g1024(NN / 64, 1024 / 64, BB);     // (16, 16, 8)

    // Q/K/V conv + BN + LIF -> f32 spike trains
    conv_qkv<<<gqkv, blk, 0, stream>>>(q_w, k_w, v_w, q_bn, k_bn, v_bn,
                                       x, q_s, k_s, v_s);

    // attention: kv = k^T v, then a = 0.125 * q kv -> LIF(0.5)  (exact fp32)
    kv_kernel<<<dim3(TT * BB * HEADS), blk, 0, stream>>>(k_s, v_s, kvb);
    attn_a_lif<<<dim3(4, 256, 8), blk, 0, stream>>>(q_s, kvb, a_s);

    // proj conv + bias + BN + LIF, fused residual: x_new = x + ssa
    conv_proj<<<g256, blk, 0, stream>>>(proj_w, proj_b, proj_bn, a_s, x_new, x);

    // MLP: 256 -> 1024 (uint8 spikes) -> 256, fused residual to d_out
    conv_mlp1<<<g1024, blk, 0, stream>>>(mlp1_w, mlp1_b, mlp1_bn, x_new, h1);
    conv_mlp2<<<g256, blk, 0, stream>>>(mlp2_w, mlp2_b, mlp2_bn, h1,
                                        (float*)d_out, x_new);
}